// Round 9
// baseline (133.556 us; speedup 1.0000x reference)
//
#include <hip/hip_runtime.h>
#include <math.h>

#define NGRID 128
#define NG2 (NGRID * NGRID)
#define NG3 (NGRID * NGRID * NGRID)
#define CH 32
#define RADC 4            // taps kept: K[5..8]/K[0] < 4e-6 — below fp32 noise vs 3e-2 threshold

constexpr float L_BOX = 10.0f;
constexpr float H = L_BOX / NGRID;   // 0.078125 — exact in fp32

struct Ktaps { float k[RADC + 1]; };

__device__ __forceinline__ float silu(float v) {
    return v / (1.0f + expf(-v));
}

// Folded 1D window value: W~[t] = sum_{a=0..3} w[a] * K[|t - 4 - a|<=4], t in 0..11.
// (cell offset = t-5 relative to base; window tap a sits at offset a-1.)
__device__ __forceinline__ float folded_tap(const float w[4], const Ktaps& K, int t) {
    float acc = 0.0f;
#pragma unroll
    for (int a = 0; a < 4; ++a) {
        int d = t - 4 - a;
        int ad = d < 0 ? -d : d;
        if (ad <= RADC) acc = fmaf(w[a], K.k[ad], acc);
    }
    return acc;
}

// One wave per particle. Cooperative 32-ch MLP via shuffles, then spread the
// z-FOLDED window (4x * 4y * 12z = 192 cells, 3 atomics/lane; the 3 cells of a
// lane share (x,y) so wx*wy is computed once).
__global__ void scatter_zfold(const int* __restrict__ z, const float* __restrict__ pos,
                              const float* __restrict__ emb,
                              const float* __restrict__ W0, const float* __restrict__ b0,
                              const float* __restrict__ W1, const float* __restrict__ b1,
                              float* __restrict__ field, Ktaps K, int N) {
    int wave = threadIdx.x >> 6, lane = threadIdx.x & 63;
    int i = blockIdx.x * 4 + wave;
    if (i >= N) return;

    // --- MLP ---
    int sub = lane & 31;                 // channel (both half-waves identical)
    int zi = z[i];
    float x = emb[zi * CH + sub];
    float acc = b0[sub];
#pragma unroll
    for (int k = 0; k < CH; ++k)
        acc = fmaf(__shfl(x, k, 32), W0[sub * CH + k], acc);
    float h1 = silu(acc);
    acc = b1[sub];
#pragma unroll
    for (int k = 0; k < CH; ++k)
        acc = fmaf(__shfl(h1, k, 32), W1[sub * CH + k], acc);
    float s = silu(acc);
#pragma unroll
    for (int m = 16; m >= 1; m >>= 1) s += __shfl_xor(s, m, 32);

    // --- window ---
    float pwx = fmodf(pos[i * 3 + 0], L_BOX);
    float pwy = fmodf(pos[i * 3 + 1], L_BOX);
    float pwz = fmodf(pos[i * 3 + 2], L_BOX);
    int bx = (int)floorf(pwx / H);
    int by = (int)floorf(pwy / H);
    int bz = (int)floorf(pwz / H);

    int px = lane & 3, py = (lane >> 2) & 3;
    int cx = bx + px - 1, cy = by + py - 1;
    float dx = (pwx - (float)cx * H) / H;
    float dy = (pwy - (float)cy * H) / H;
    float wxy = s * expf(-0.5f * dx * dx) * expf(-0.5f * dy * dy);
    int ix = (cx + NGRID) & 127, iy = (cy + NGRID) & 127;
    int xybase = iy * NGRID + ix;

    float wz[4];
#pragma unroll
    for (int a = 0; a < 4; ++a) {
        float dz = (pwz - (float)(bz + a - 1) * H) / H;
        wz[a] = expf(-0.5f * dz * dz);
    }

#pragma unroll
    for (int k = 0; k < 3; ++k) {
        int t = (lane >> 4) + 4 * k;                 // 0..11, each covered once per (px,py)
        float wt = folded_tap(wz, K, t) * wxy;
        int izc = (bz + t - 5 + NGRID) & 127;        // cell z = bz + (t-5)
        atomicAdd(&field[izc * NG2 + xybase], wt);
    }
}

// One wave per particle: gather with x,y-FOLDED windows
// (12x * 12y * 4z = 576 cells, 9 loads/lane), butterfly-reduce, lane 0 stores.
__global__ void gather_xyfold(const float* __restrict__ pos,
                              const float* __restrict__ field,
                              float* __restrict__ out, Ktaps K, int N) {
    int wave = threadIdx.x >> 6, lane = threadIdx.x & 63;
    int i = blockIdx.x * 4 + wave;
    if (i >= N) return;

    float pwx = fmodf(pos[i * 3 + 0], L_BOX);
    float pwy = fmodf(pos[i * 3 + 1], L_BOX);
    float pwz = fmodf(pos[i * 3 + 2], L_BOX);
    int bx = (int)floorf(pwx / H);
    int by = (int)floorf(pwy / H);
    int bz = (int)floorf(pwz / H);

    float wx[4], wy[4], wz[4];
#pragma unroll
    for (int a = 0; a < 4; ++a) {
        float dx = (pwx - (float)(bx + a - 1) * H) / H;
        float dy = (pwy - (float)(by + a - 1) * H) / H;
        float dz = (pwz - (float)(bz + a - 1) * H) / H;
        wx[a] = expf(-0.5f * dx * dx);
        wy[a] = expf(-0.5f * dy * dy);
        wz[a] = expf(-0.5f * dz * dz);
    }

    // Precompute folded 1D tables (12 each) — cheap VALU, avoids per-cell refold.
    float fx[12], fy[12];
#pragma unroll
    for (int t = 0; t < 12; ++t) {
        fx[t] = folded_tap(wx, K, t);
        fy[t] = folded_tap(wy, K, t);
    }

    float e = 0.0f;
#pragma unroll
    for (int k = 0; k < 9; ++k) {
        int c = lane + 64 * k;           // 0..575 unique
        int xi = c % 12;
        int rest = c / 12;
        int yi = rest % 12;
        int zi = rest / 12;              // 0..3
        int gx = (bx + xi - 5 + NGRID) & 127;
        int gy = (by + yi - 5 + NGRID) & 127;
        int gz = (bz + zi - 1 + NGRID) & 127;
        float wt = fx[xi] * fy[yi] * wz[zi];
        e += wt * field[gz * NG2 + gy * NGRID + gx];
    }
#pragma unroll
    for (int m = 32; m >= 1; m >>= 1) e += __shfl_xor(e, m, 64);
    if (lane == 0) out[i] = e;
}

extern "C" void kernel_launch(void* const* d_in, const int* in_sizes, int n_in,
                              void* d_out, int out_size, void* d_ws, size_t ws_size,
                              hipStream_t stream) {
    const int*   z   = (const int*)d_in[0];
    const float* pos = (const float*)d_in[1];
    // d_in[2] = batch: all zeros with NBATCH=1 -> no effect on flat index.
    const float* emb = (const float*)d_in[3];
    const float* W0  = (const float*)d_in[4];
    const float* b0  = (const float*)d_in[5];
    const float* W1  = (const float*)d_in[6];
    const float* b1  = (const float*)d_in[7];
    int N = in_sizes[0];

    float* field = (float*)d_ws;          // 8 MB

    // Host-side exact periodic taps: inverse DFT of exp(-0.5*(2*pi*j'/NG)^2).
    // Pure function of compile-time constants — identical every call.
    Ktaps K;
    for (int r = 0; r <= RADC; ++r) {
        double acc = 0.0;
        for (int j = 0; j < NGRID; ++j) {
            int jj = (j < NGRID / 2) ? j : j - NGRID;
            double arg = (2.0 * M_PI * jj) / NGRID;   // sigma = h cancels
            acc += exp(-0.5 * arg * arg) * cos((2.0 * M_PI) * ((double)(j * r) / NGRID));
        }
        K.k[r] = (float)(acc / NGRID);
    }

    hipMemsetAsync(field, 0, NG3 * sizeof(float), stream);
    scatter_zfold<<<(N + 3) / 4, 256, 0, stream>>>(z, pos, emb, W0, b0, W1, b1, field, K, N);
    gather_xyfold<<<(N + 3) / 4, 256, 0, stream>>>(pos, field, (float*)d_out, K, N);
}

// Round 10
// 118.472 us; speedup vs baseline: 1.1273x; 1.1273x over previous
//
#include <hip/hip_runtime.h>
#include <math.h>

#define NGRID 128
#define NG2 (NGRID * NGRID)
#define NG3 (NGRID * NGRID * NGRID)
#define CH 32
#define RADC 4            // taps kept: K[5..8]/K[0] < 4e-6 — below fp32 noise vs 3e-2 threshold
#define YT 32             // y-tile height in conv_xy
#define HALO RADC
#define ROWS (YT + 2 * HALO)   // 40

constexpr float L_BOX = 10.0f;
constexpr float H = L_BOX / NGRID;   // 0.078125 — exact in fp32

struct Ktaps { float k[RADC + 1]; };

__device__ __forceinline__ float silu(float v) {
    return v / (1.0f + expf(-v));
}

// Per-lane window: lane handles tap (px,py,pz); returns weight and flat index.
__device__ __forceinline__ void lane_tap(const float* __restrict__ pos, int i, int lane,
                                         float& w, int& addr) {
    int px = lane & 3, py = (lane >> 2) & 3, pz = (lane >> 4) & 3;
    float pwx = fmodf(pos[i * 3 + 0], L_BOX);
    float pwy = fmodf(pos[i * 3 + 1], L_BOX);
    float pwz = fmodf(pos[i * 3 + 2], L_BOX);
    int bx = (int)floorf(pwx / H);
    int by = (int)floorf(pwy / H);
    int bz = (int)floorf(pwz / H);
    int cx = bx + px - 1, cy = by + py - 1, cz = bz + pz - 1;
    float dx = (pwx - (float)cx * H) / H;
    float dy = (pwy - (float)cy * H) / H;
    float dz = (pwz - (float)cz * H) / H;
    w = expf(-0.5f * dx * dx) * expf(-0.5f * dy * dy) * expf(-0.5f * dz * dz);
    int ix = (cx + NGRID) & (NGRID - 1);
    int iy = (cy + NGRID) & (NGRID - 1);
    int iz = (cz + NGRID) & (NGRID - 1);
    addr = iz * NG2 + iy * NGRID + ix;
}

// One wave per particle: cooperative 32-ch MLP via shuffles, one NATIVE fp32
// atomic per lane (global_atomic_add_f32 — no CAS loop).
__global__ void scatter_wave(const int* __restrict__ z, const float* __restrict__ pos,
                             const float* __restrict__ emb,
                             const float* __restrict__ W0, const float* __restrict__ b0,
                             const float* __restrict__ W1, const float* __restrict__ b1,
                             float* __restrict__ field, int N) {
    int wave = threadIdx.x >> 6, lane = threadIdx.x & 63;
    int i = blockIdx.x * 4 + wave;
    if (i >= N) return;
    int sub = lane & 31;                 // channel (both half-waves identical)
    int zi = z[i];
    float x = emb[zi * CH + sub];

    float acc = b0[sub];
#pragma unroll
    for (int k = 0; k < CH; ++k)
        acc = fmaf(__shfl(x, k, 32), W0[sub * CH + k], acc);
    float h1 = silu(acc);

    acc = b1[sub];
#pragma unroll
    for (int k = 0; k < CH; ++k)
        acc = fmaf(__shfl(h1, k, 32), W1[sub * CH + k], acc);
    float s = silu(acc);
#pragma unroll
    for (int m = 16; m >= 1; m >>= 1) s += __shfl_xor(s, m, 32);

    float w; int addr;
    lane_tap(pos, i, lane, w, addr);
    unsafeAtomicAdd(&field[addr], w * s);   // native global_atomic_add_f32
}

// Fused x+y circular conv for one z-plane y-tile. Reads fin, writes fout
// (separate buffer: no cross-block in-place race). LDS tile has y-halo of
// RADC rows each side; x-conv is done in place by wave-private rows (lockstep
// SIMD: all reads of a row issue before its writes), then one barrier, y-conv.
__global__ void __launch_bounds__(256)
conv_xy(const float* __restrict__ fin, float* __restrict__ fout, Ktaps K) {
    __shared__ float sm[ROWS][NGRID];    // 40*128*4 = 20 KB
    int zpl = blockIdx.x >> 2;           // z plane
    int y0  = (blockIdx.x & 3) * YT;     // y tile origin
    int tid = threadIdx.x;
    const float* plane = fin + zpl * NG2;

    for (int idx = tid; idx < ROWS * NGRID; idx += 256) {
        int row = idx >> 7, x = idx & 127;
        int gy = (y0 + row - HALO) & (NGRID - 1);
        sm[row][x] = plane[gy * NGRID + x];
    }
    __syncthreads();

    // x-conv (circular in x, fully resident in LDS), wave-private rows
    int wave = tid >> 6, lane = tid & 63;
    for (int row = wave; row < ROWS; row += 4) {
        int t0 = lane, t1 = lane + 64;
        float a0 = K.k[0] * sm[row][t0];
        float a1 = K.k[0] * sm[row][t1];
#pragma unroll
        for (int r = 1; r <= RADC; ++r) {
            a0 += K.k[r] * (sm[row][(t0 + r) & 127] + sm[row][(t0 - r + 128) & 127]);
            a1 += K.k[r] * (sm[row][(t1 + r) & 127] + sm[row][(t1 - r + 128) & 127]);
        }
        sm[row][t0] = a0;
        sm[row][t1] = a1;
    }
    __syncthreads();

    // y-conv (halo covers +-RADC), coalesced write to output buffer
    int xl = tid & 127, yh = tid >> 7;   // yh = 0..1
    float* oplane = fout + zpl * NG2;
    for (int j = yh; j < YT; j += 2) {
        float acc = K.k[0] * sm[HALO + j][xl];
#pragma unroll
        for (int r = 1; r <= RADC; ++r)
            acc += K.k[r] * (sm[HALO + j + r][xl] + sm[HALO + j - r][xl]);
        oplane[(y0 + j) * NGRID + xl] = acc;
    }
}

// Gather with the z-conv folded into the particle's z-window:
// energy_i = sum_{px,py} wx*wy * sum_{zc} Wz~(zc) * field_xy(ix,iy,zc)
// where Wz~ = wz (*) K has support 4+2*RADC = 12 cells (we scan 16 for
// uniform lanes; wt==0 slots skip their load).
// Lane = (px, py, z-group); each lane does <=4 strided loads, butterfly-reduce.
__global__ void gather_z(const float* __restrict__ pos,
                         const float* __restrict__ field2,
                         float* __restrict__ out, Ktaps K, int N) {
    int wave = threadIdx.x >> 6, lane = threadIdx.x & 63;
    int i = blockIdx.x * 4 + wave;
    if (i >= N) return;
    int px = lane & 3, py = (lane >> 2) & 3, zg = lane >> 4;   // zg = 0..3

    float pwx = fmodf(pos[i * 3 + 0], L_BOX);
    float pwy = fmodf(pos[i * 3 + 1], L_BOX);
    float pwz = fmodf(pos[i * 3 + 2], L_BOX);
    int bx = (int)floorf(pwx / H);
    int by = (int)floorf(pwy / H);
    int bz = (int)floorf(pwz / H);
    int cx = bx + px - 1, cy = by + py - 1;
    float dx = (pwx - (float)cx * H) / H;
    float dy = (pwy - (float)cy * H) / H;
    float wxy = expf(-0.5f * dx * dx) * expf(-0.5f * dy * dy);
    int ix = (cx + NGRID) & 127, iy = (cy + NGRID) & 127;

    float wz[4];
#pragma unroll
    for (int pz = 0; pz < 4; ++pz) {
        int cz = bz + pz - 1;
        float dz = (pwz - (float)cz * H) / H;
        wz[pz] = expf(-0.5f * dz * dz);
    }

    int xybase = iy * NGRID + ix;
    float e = 0.0f;
#pragma unroll
    for (int jj = 0; jj < 4; ++jj) {
        int zo = zg * 4 + jj;            // 0..15
        int zc = bz - 7 + zo;            // support really [bz-5, bz+7]
        float wt = 0.0f;
#pragma unroll
        for (int pz = 0; pz < 4; ++pz) {
            int d = zo - 6 - pz;         // zc - (bz+pz-1), bz cancels
            unsigned ud = (unsigned)(d + RADC);
            if (ud <= 2 * RADC) wt += wz[pz] * K.k[d < 0 ? -d : d];
        }
        if (wt != 0.0f)
            e += wt * field2[((zc + NGRID) & 127) * NG2 + xybase];
    }
    e *= wxy;
#pragma unroll
    for (int m = 32; m >= 1; m >>= 1) e += __shfl_xor(e, m, 64);
    if (lane == 0) out[i] = e;
}

extern "C" void kernel_launch(void* const* d_in, const int* in_sizes, int n_in,
                              void* d_out, int out_size, void* d_ws, size_t ws_size,
                              hipStream_t stream) {
    const int*   z   = (const int*)d_in[0];
    const float* pos = (const float*)d_in[1];
    // d_in[2] = batch: all zeros with NBATCH=1 -> no effect on flat index.
    const float* emb = (const float*)d_in[3];
    const float* W0  = (const float*)d_in[4];
    const float* b0  = (const float*)d_in[5];
    const float* W1  = (const float*)d_in[6];
    const float* b1  = (const float*)d_in[7];
    int N = in_sizes[0];

    float* field1 = (float*)d_ws;         // scatter target, 8 MB
    float* field2 = field1 + NG3;         // xy-conv output, 8 MB

    // Host-side exact periodic taps: inverse DFT of exp(-0.5*(2*pi*j'/NG)^2).
    // Pure function of compile-time constants — identical every call.
    Ktaps K;
    for (int r = 0; r <= RADC; ++r) {
        double acc = 0.0;
        for (int j = 0; j < NGRID; ++j) {
            int jj = (j < NGRID / 2) ? j : j - NGRID;
            double arg = (2.0 * M_PI * jj) / NGRID;   // sigma = h cancels
            acc += exp(-0.5 * arg * arg) * cos((2.0 * M_PI) * ((double)(j * r) / NGRID));
        }
        K.k[r] = (float)(acc / NGRID);
    }

    hipMemsetAsync(field1, 0, NG3 * sizeof(float), stream);
    scatter_wave<<<(N + 3) / 4, 256, 0, stream>>>(z, pos, emb, W0, b0, W1, b1, field1, N);
    conv_xy<<<NGRID * 4, 256, 0, stream>>>(field1, field2, K);
    gather_z<<<(N + 3) / 4, 256, 0, stream>>>(pos, field2, (float*)d_out, K, N);
}